// Round 10
// baseline (1178.326 us; speedup 1.0000x reference)
//
#include <hip/hip_runtime.h>
#include <hip/hip_bf16.h>
#include <math.h>

#define NB 4
#define SEQ 1024
#define DM 512
#define DB 256
#define G3 768
#define CO 32
#define TONS 8192
#define POOLN 8
#define TOCT 1024
#define NH 8
#define DHD 32

// weight K-slice split: Kt 0..RKT-1 in VGPRs, Kt RKT..7 in LDS
#define RKT 6
#define LKT 2

// workspace float offsets
#define OFF_GI     0u            // 4096*768
#define OFF_GIBAR  3145728u      // 4096*768
#define OFF_HEND   6291456u      // 4096*256
#define OFF_GALL   7340032u      // 4096*256
#define OFF_KMAT   8388608u      // 4096*256
#define OFF_WFN    9437184u      // 24576 uint4 = MFMA B-frag Whh_note (bf16)
#define OFF_WFB    9633792u      // 24576 uint4 = MFMA B-frag Whh_bar
#define OFF_INT_BYTES 39321600u  // ints after floats

#define OUT_FINAL 4096
#define OUT_CARR  5120

typedef __attribute__((ext_vector_type(8))) short short8v;  // 8 bf16 (4 VGPR)
typedef __attribute__((ext_vector_type(4))) float f32x4;

__device__ __forceinline__ unsigned int bf16rne(float f) {
    unsigned int u = __float_as_uint(f);
    return (u + 0x7fffu + ((u >> 16) & 1u)) >> 16;
}

// ---------- K0: mask dtype detection + per-batch scan + flattened segment list ----------
__global__ __launch_bounds__(256) void k_scan(const unsigned char* __restrict__ mraw,
        int* __restrict__ pos, int* __restrict__ lastk, int* __restrict__ nmask,
        int* __restrict__ sS, int* __restrict__ sLen, int* __restrict__ sC,
        int* __restrict__ nseg) {
    __shared__ int rnz[8];
    __shared__ int gt1;
    __shared__ int mode;
    __shared__ int snm[NB];
    int tid = threadIdx.x;
    if (tid < 8) rnz[tid] = 0;
    if (tid == 0) gt1 = 0;
    __syncthreads();
    for (int i = tid; i < NB * SEQ; i += 256) {
        unsigned char v = mraw[i];
        if (v) {
            rnz[i & 7] = 1;          // benign same-value race
            if (v > 1) gt1 = 1;
        }
    }
    __syncthreads();
    if (tid == 0) {
        bool lowhalf = rnz[0] | rnz[1] | rnz[4] | rnz[5];
        bool hihalf  = rnz[2] | rnz[3] | rnz[6] | rnz[7];
        int m;
        if (hihalf && !lowhalf) {
            m = (rnz[2] | rnz[3]) ? 3 : 4;          // f32 : f64
        } else if (gt1) {
            m = 5;                                   // 16-bit float-ish
        } else if (rnz[1] | rnz[3] | rnz[5] | rnz[7]) {
            m = 0;                                   // u8 bool
        } else if (rnz[4]) {
            m = 1;                                   // i32
        } else if (rnz[0]) {
            m = 2;                                   // i64
        } else {
            m = 0;
        }
        mode = m;
    }
    __syncthreads();
    if (tid < NB) {
        int b = tid;
        int cnt = 0;
        for (int t = 0; t < SEQ; ++t) {
            int idx = b * SEQ + t;
            int mv;
            switch (mode) {
                case 0:  mv = mraw[idx] != 0; break;
                case 1:  mv = ((const int*)mraw)[idx] != 0; break;
                case 2:  mv = ((const long long*)mraw)[idx] != 0LL; break;
                case 3:  mv = ((const float*)mraw)[idx] != 0.f; break;
                case 4:  mv = ((const double*)mraw)[idx] != 0.0; break;
                default: mv = ((const unsigned short*)mraw)[idx] != 0; break;
            }
            if (mv) { pos[b * SEQ + cnt] = t; ++cnt; }
            lastk[idx] = cnt - 1;
        }
        nmask[b] = cnt;
        snm[b] = cnt;
    }
    __syncthreads();
    if (tid < NB) {
        int b = tid;
        int base = 0;
        for (int x = 0; x < b; ++x) base += snm[x];
        int cnt = snm[b];
        for (int k = 0; k < cnt; ++k) {
            int e = pos[b * SEQ + k];
            int s = (k == 0) ? 0 : (pos[b * SEQ + k - 1] + 1);
            sS[base + k]   = b * SEQ + s;     // global gi row of first step
            sLen[base + k] = e - s;           // number of GRU steps
            sC[base + k]   = b * SEQ + k;     // chain id (hend row)
        }
    }
    __syncthreads();
    if (tid == 0) {
        int t = 0;
        for (int x = 0; x < NB; ++x) t += snm[x];
        *nseg = t;
    }
}

// ---------- pack Whh (768x256 f32) into MFMA B-fragment order (bf16) ----------
// frag idx4 = (T*8 + Kt)*64 + lane ; holds W[16T + (lane&15)][32Kt + (lane>>4)*8 + 0..7]
__global__ __launch_bounds__(256) void k_wfrag(const float* __restrict__ W, uint4* __restrict__ out) {
    int idx = blockIdx.x * 256 + threadIdx.x;
    if (idx >= 48 * 8 * 64) return;
    int lane = idx & 63;
    int TK = idx >> 6;
    int T = TK >> 3, Kt = TK & 7;
    int row = 16 * T + (lane & 15);
    int kb = 32 * Kt + (lane >> 4) * 8;
    const float* wr = W + (size_t)row * DB + kb;
    uint4 u;
    u.x = bf16rne(wr[0]) | (bf16rne(wr[1]) << 16);
    u.y = bf16rne(wr[2]) | (bf16rne(wr[3]) << 16);
    u.z = bf16rne(wr[4]) | (bf16rne(wr[5]) << 16);
    u.w = bf16rne(wr[6]) | (bf16rne(wr[7]) << 16);
    out[idx] = u;
}

// ---------- tiled NT GEMM: C[m][n] = bias[n] + sum_k A[m*K+k]*Bm[n*K+k] ----------
__global__ __launch_bounds__(256) void k_gemm_nt(int M, int N, int K,
        const float* __restrict__ A, const float* __restrict__ Bm,
        const float* __restrict__ bias, float* __restrict__ C) {
    __shared__ __align__(16) float As2[32][68];
    __shared__ __align__(16) float Bs2[32][68];
    int bm = blockIdx.y * 64, bn = blockIdx.x * 64;
    int tid = threadIdx.x;
    int tx = tid & 15, ty = tid >> 4;
    float acc[4][4] = {};
    for (int k0 = 0; k0 < K; k0 += 32) {
        for (int i = tid; i < 64 * 32; i += 256) {
            int r = i >> 5, c = i & 31;
            As2[c][r] = A[(size_t)(bm + r) * K + k0 + c];
            Bs2[c][r] = Bm[(size_t)(bn + r) * K + k0 + c];
        }
        __syncthreads();
#pragma unroll
        for (int kk = 0; kk < 32; ++kk) {
            float4 av = *reinterpret_cast<const float4*>(&As2[kk][ty * 4]);
            float4 bv = *reinterpret_cast<const float4*>(&Bs2[kk][tx * 4]);
            float a[4] = {av.x, av.y, av.z, av.w};
            float b[4] = {bv.x, bv.y, bv.z, bv.w};
#pragma unroll
            for (int i = 0; i < 4; ++i)
#pragma unroll
                for (int j = 0; j < 4; ++j) acc[i][j] += a[i] * b[j];
        }
        __syncthreads();
    }
#pragma unroll
    for (int i = 0; i < 4; ++i)
#pragma unroll
        for (int j = 0; j < 4; ++j)
            C[(size_t)(bm + ty * 4 + i) * N + bn + tx * 4 + j] = acc[i][j] + bias[bn + tx * 4 + j];
}

// ---------- K matrix: pooled onset + sinusoidal PE, project 32->256 ----------
__global__ __launch_bounds__(64) void k_keys(const float* __restrict__ onset,
        const float* __restrict__ Wk, const float* __restrict__ bk, float* __restrict__ Kmat) {
    int bt = blockIdx.x;
    int b = bt >> 10, t = bt & 1023;
    __shared__ float xin[CO];
    int tid = threadIdx.x;
    if (tid < CO) {
        float s = 0.f;
        const float* base = onset + ((size_t)b * TONS + (size_t)t * POOLN) * CO + tid;
#pragma unroll
        for (int p = 0; p < POOLN; ++p) s += base[p * CO];
        s *= (1.f / POOLN);
        int j = tid >> 1;
        float dv = expf(-logf(10000.f) * (float)j / 16.f);
        float ang = (float)t * dv;
        s += (tid & 1) ? cosf(ang) : sinf(ang);
        xin[tid] = s;
    }
    __syncthreads();
    for (int n = tid; n < DB; n += 64) {
        float acc = bk[n];
        const float* wr = Wk + (size_t)n * CO;
#pragma unroll
        for (int c = 0; c < CO; ++c) acc += xin[c] * wr[c];
        Kmat[(size_t)bt * DB + n] = acc;
    }
}

// ---------- MFMA-batched GRU, hybrid reg+LDS weights, gx prefetch, 1 barrier/step ----------
// 16 segments per block; gh(16x768) = H(16x256) @ Whh^T per step.
// 512 thr = 8 waves; wave w owns tiles t=0..5 (t=2g+ii -> T=16g+2w+ii).
template<int MODE>
__global__ __launch_bounds__(512, 1) void k_gru(
        const uint4* __restrict__ wf, const float* __restrict__ bhh,
        const float* __restrict__ gx_src,
        const int* __restrict__ sS, const int* __restrict__ sLen,
        const int* __restrict__ sC, const int* __restrict__ nseg_p,
        const int* __restrict__ nmask, float* __restrict__ outp) {
    int bg = blockIdx.x;
    int nseg = (MODE == 0) ? *nseg_p : NB;
    if (16 * bg >= nseg) return;
    int tid = threadIdx.x;
    int w = tid >> 6;
    int lane = tid & 63;
    int lhi = lane >> 4, c = lane & 15;

    __shared__ __align__(16) unsigned short hfrag[2][8 * 64 * 8];        // 2x8 KB, A-frag dbuf
    __shared__ __align__(16) uint4 wlds[8 * 6 * LKT * 64];               // 98 KB, B-frag slices

    // one-time weight residency load (wlds region is wave-private: written+read by same wave)
    uint4 wreg[6][RKT];
#pragma unroll
    for (int t = 0; t < 6; ++t) {
        int T = 16 * (t >> 1) + 2 * w + (t & 1);
#pragma unroll
        for (int kt = 0; kt < RKT; ++kt)
            wreg[t][kt] = wf[(size_t)(T * 8 + kt) * 64 + lane];
#pragma unroll
        for (int kt = 0; kt < LKT; ++kt)
            wlds[((w * 6 + t) * LKT + kt) * 64 + lane] = wf[(size_t)(T * 8 + RKT + kt) * 64 + lane];
    }

    int ss_r[4], len_r[4], sc_r[4];
#pragma unroll
    for (int r = 0; r < 4; ++r) {
        int m = 4 * lhi + r;
        int gs = 16 * bg + m;
        if (MODE == 0) {
            bool v = gs < nseg;
            ss_r[r]  = v ? sS[gs] : 0;
            len_r[r] = v ? sLen[gs] : 0;
            sc_r[r]  = v ? sC[gs] : 0;
        } else {
            bool v = m < NB;
            ss_r[r]  = v ? m * SEQ : 0;
            len_r[r] = v ? nmask[m] : 0;
            sc_r[r]  = 0;
        }
    }
    int mx = 0;
    for (int q = 0; q < 16; ++q) {
        int gs = 16 * bg + q;
        int L = (MODE == 0) ? ((gs < nseg) ? sLen[gs] : 0)
                            : ((q < NB) ? nmask[q] : 0);
        mx = max(mx, L);
    }
    float bh[3][2];
#pragma unroll
    for (int g = 0; g < 3; ++g)
#pragma unroll
        for (int ii = 0; ii < 2; ++ii)
            bh[g][ii] = bhh[g * 256 + 32 * w + 16 * ii + c];
    float h[4][2] = {};

#define LOADGX(dst, step)                                                        \
    {                                                                            \
        int i_ = (step);                                                         \
        _Pragma("unroll")                                                        \
        for (int r = 0; r < 4; ++r) {                                            \
            int row = (i_ < len_r[r]) ? (ss_r[r] + i_) : ss_r[r];                \
            const float* gp = gx_src + (size_t)row * G3 + 32 * w + c;            \
            _Pragma("unroll")                                                    \
            for (int g = 0; g < 3; ++g)                                          \
                _Pragma("unroll")                                                \
                for (int ii = 0; ii < 2; ++ii)                                   \
                    dst[g][ii][r] = gp[g * 256 + 16 * ii];                       \
        }                                                                        \
    }

    float gxa[3][2][4], gxb[3][2][4];
    if (mx > 0) LOADGX(gxa, 0)
    int buf = 0;

    for (int i = 0; i < mx; ++i) {
        // prefetch next step's gx (overlaps with MFMA/LDS below)
        LOADGX(gxb, i + 1)
        f32x4 acc[6];
#pragma unroll
        for (int t = 0; t < 6; ++t) acc[t] = (f32x4){0.f, 0.f, 0.f, 0.f};
        if (i > 0) {
            const short8v* hf8 = (const short8v*)hfrag[buf];
#pragma unroll
            for (int kt = 0; kt < 8; ++kt) {
                short8v a = hf8[kt * 64 + lane];
                if (kt < RKT) {
#pragma unroll
                    for (int t = 0; t < 6; ++t) {
                        short8v bv = __builtin_bit_cast(short8v, wreg[t][kt]);
                        acc[t] = __builtin_amdgcn_mfma_f32_16x16x32_bf16(a, bv, acc[t], 0, 0, 0);
                    }
                } else {
#pragma unroll
                    for (int t = 0; t < 6; ++t) {
                        uint4 u = wlds[((w * 6 + t) * LKT + (kt - RKT)) * 64 + lane];
                        short8v bv = __builtin_bit_cast(short8v, u);
                        acc[t] = __builtin_amdgcn_mfma_f32_16x16x32_bf16(a, bv, acc[t], 0, 0, 0);
                    }
                }
            }
        }
        // gate math; D layout: m=(lane>>4)*4+r at vector elem r, col=lane&15; tile t=2g+ii
#pragma unroll
        for (int r = 0; r < 4; ++r) {
#pragma unroll
            for (int ii = 0; ii < 2; ++ii) {
                float rr = 1.f / (1.f + expf(-(gxa[0][ii][r] + bh[0][ii] + acc[0 + ii][r])));
                float zz = 1.f / (1.f + expf(-(gxa[1][ii][r] + bh[1][ii] + acc[2 + ii][r])));
                float nn = tanhf(gxa[2][ii][r] + rr * (bh[2][ii] + acc[4 + ii][r]));
                float hv = (1.f - zz) * nn + zz * h[r][ii];
                bool act = i < len_r[r];
                hv = act ? hv : h[r][ii];
                h[r][ii] = hv;
                if (MODE == 1) {
                    if (lhi == 0 && act) {   // m = r < NB
                        int j = 32 * w + 16 * ii + c;
                        outp[(size_t)(ss_r[r] + i) * DB + j] = hv;
                    }
                }
            }
        }
        // write next A-frag to the OTHER buffer; single barrier makes it visible
        // and guarantees this iter's reads of hfrag[buf] completed block-wide.
#pragma unroll
        for (int r = 0; r < 4; ++r)
#pragma unroll
            for (int ii = 0; ii < 2; ++ii) {
                int j = 32 * w + 16 * ii + c;        // j>>5 == w
                int m = 4 * lhi + r;
                int lp = m + 16 * ((j >> 3) & 3);
                hfrag[buf ^ 1][(size_t)(w * 64 + lp) * 8 + (j & 7)] =
                    (unsigned short)bf16rne(h[r][ii]);
            }
        __syncthreads();
        buf ^= 1;
        // rotate prefetched gx into current (static copy)
#pragma unroll
        for (int g = 0; g < 3; ++g)
#pragma unroll
            for (int ii = 0; ii < 2; ++ii)
#pragma unroll
                for (int r = 0; r < 4; ++r)
                    gxa[g][ii][r] = gxb[g][ii][r];
    }
#undef LOADGX
    if (MODE == 0) {
#pragma unroll
        for (int r = 0; r < 4; ++r) {
            int gs = 16 * bg + 4 * lhi + r;
            if (gs < nseg) {
#pragma unroll
                for (int ii = 0; ii < 2; ++ii)
                    outp[(size_t)sc_r[r] * DB + 32 * w + 16 * ii + c] = h[r][ii];
            }
        }
    }
}

// ---------- fill outputs: h_bar_carried, h_bar_final, zero com ----------
__global__ __launch_bounds__(256) void k_fill(const float* __restrict__ gall,
        const int* __restrict__ lastk, const int* __restrict__ nmask,
        float* __restrict__ out) {
    int bt = blockIdx.x;
    int b = bt >> 10, t = bt & 1023;
    int tid = threadIdx.x;
    int lk = lastk[bt];
    float v = (lk >= 0) ? gall[((size_t)b * SEQ + lk) * DB + tid] : 0.f;
    out[OUT_CARR + (size_t)bt * DB + tid] = v;
    if (tid == 0) out[bt] = 0.f;
    if (t == 0) {
        int nm = nmask[b];
        float fv = (nm > 0) ? gall[((size_t)b * SEQ + nm - 1) * DB + tid] : 0.f;
        out[OUT_FINAL + b * DB + tid] = fv;
    }
}

// ---------- attention + com at mask rows only ----------
__global__ __launch_bounds__(256) void k_attn(const float* __restrict__ gall,
        const float* __restrict__ Wq, const float* __restrict__ bq,
        const float* __restrict__ Kmat, const int* __restrict__ pos,
        const int* __restrict__ nmask, const float* __restrict__ pbs_ptr,
        float* __restrict__ out) {
    int c = blockIdx.x;
    int b = c >> 10, k = c & 1023;
    if (k >= nmask[b]) return;
    int trow = pos[b * SEQ + k];
    __shared__ float q[DB];
    __shared__ float grow[DB];
    __shared__ float sc[NH][TOCT];
    __shared__ float comh[NH];
    int tid = threadIdx.x;
    grow[tid] = gall[((size_t)b * SEQ + k) * DB + tid];
    __syncthreads();
    {
        float acc = bq[tid];
        const float* wr = Wq + (size_t)tid * DB;
#pragma unroll 4
        for (int j = 0; j < DB; ++j) acc += grow[j] * wr[j];
        q[tid] = acc;
    }
    __syncthreads();
    float pbs = *pbs_ptr;
    const float scale = 0.17677669529663687f; // 1/sqrt(32)
    for (int t = tid; t < TOCT; t += 256) {
        const float* kr = Kmat + ((size_t)b * TOCT + t) * DB;
        float tp = (float)t * (1.f / 1023.f);
#pragma unroll
        for (int h = 0; h < NH; ++h) {
            float acc = 0.f;
#pragma unroll
            for (int d = 0; d < DHD; ++d) acc += q[h * DHD + d] * kr[h * DHD + d];
            sc[h][t] = acc * scale - pbs * tp;
        }
    }
    __syncthreads();
    int hh = tid >> 5, l = tid & 31;
    float mx = -1e30f;
    for (int t = l; t < TOCT; t += 32) mx = fmaxf(mx, sc[hh][t]);
#pragma unroll
    for (int o = 16; o > 0; o >>= 1) mx = fmaxf(mx, __shfl_xor(mx, o, 32));
    float se = 0.f, sw = 0.f;
    for (int t = l; t < TOCT; t += 32) {
        float e = expf(sc[hh][t] - mx);
        se += e;
        sw += e * ((float)t * (1.f / 1023.f));
    }
#pragma unroll
    for (int o = 16; o > 0; o >>= 1) { se += __shfl_xor(se, o, 32); sw += __shfl_xor(sw, o, 32); }
    if (l == 0) comh[hh] = sw / se;
    __syncthreads();
    if (tid == 0) {
        float cm = 0.f;
#pragma unroll
        for (int h = 0; h < NH; ++h) cm += comh[h];
        out[b * SEQ + trow] = cm * (1.f / NH);
    }
}

extern "C" void kernel_launch(void* const* d_in, const int* in_sizes, int n_in,
                              void* d_out, int out_size, void* d_ws, size_t ws_size,
                              hipStream_t stream) {
    const float* te    = (const float*)d_in[0];
    const float* onset = (const float*)d_in[1];
    const unsigned char* mask = (const unsigned char*)d_in[2];
    const float* Wih_n = (const float*)d_in[3];
    const float* Whh_n = (const float*)d_in[4];
    const float* bih_n = (const float*)d_in[5];
    const float* bhh_n = (const float*)d_in[6];
    const float* Wih_b = (const float*)d_in[7];
    const float* Whh_b = (const float*)d_in[8];
    const float* bih_b = (const float*)d_in[9];
    const float* bhh_b = (const float*)d_in[10];
    const float* Wq    = (const float*)d_in[11];
    const float* bq    = (const float*)d_in[12];
    const float* Wk    = (const float*)d_in[13];
    const float* bk    = (const float*)d_in[14];
    const float* pbs   = (const float*)d_in[15];
    float* out = (float*)d_out;

    float* ws    = (float*)d_ws;
    float* gi    = ws + OFF_GI;
    float* gibar = ws + OFF_GIBAR;
    float* hend  = ws + OFF_HEND;
    float* gall  = ws + OFF_GALL;
    float* kmat  = ws + OFF_KMAT;
    uint4* wfn   = (uint4*)(ws + OFF_WFN);
    uint4* wfb   = (uint4*)(ws + OFF_WFB);
    int* ipos    = (int*)((char*)d_ws + OFF_INT_BYTES);
    int* ilastk  = ipos + NB * SEQ;
    int* inmask  = ilastk + NB * SEQ;
    int* isS     = inmask + NB;
    int* isLen   = isS + NB * SEQ;
    int* isC     = isLen + NB * SEQ;
    int* inseg   = isC + NB * SEQ;

    k_scan<<<1, 256, 0, stream>>>(mask, ipos, ilastk, inmask, isS, isLen, isC, inseg);
    k_wfrag<<<96, 256, 0, stream>>>(Whh_n, wfn);
    k_wfrag<<<96, 256, 0, stream>>>(Whh_b, wfb);
    k_gemm_nt<<<dim3(G3 / 64, (NB * SEQ) / 64), 256, 0, stream>>>(NB * SEQ, G3, DM, te, Wih_n, bih_n, gi);
    k_keys<<<NB * TOCT, 64, 0, stream>>>(onset, Wk, bk, kmat);
    k_gru<0><<<256, 512, 0, stream>>>(wfn, bhh_n, gi, isS, isLen, isC, inseg, inmask, hend);
    k_gemm_nt<<<dim3(G3 / 64, (NB * SEQ) / 64), 256, 0, stream>>>(NB * SEQ, G3, DB, hend, Wih_b, bih_b, gibar);
    k_gru<1><<<1, 512, 0, stream>>>(wfb, bhh_b, gibar, isS, isLen, isC, inseg, inmask, gall);
    k_fill<<<NB * SEQ, 256, 0, stream>>>(gall, ilastk, inmask, out);
    k_attn<<<NB * SEQ, 256, 0, stream>>>(gall, Wq, bq, kmat, ipos, inmask, pbs, out);
}

// Round 11
// 981.207 us; speedup vs baseline: 1.2009x; 1.2009x over previous
//
#include <hip/hip_runtime.h>
#include <hip/hip_bf16.h>
#include <math.h>

#define NB 4
#define SEQ 1024
#define DM 512
#define DB 256
#define G3 768
#define CO 32
#define TONS 8192
#define POOLN 8
#define TOCT 1024
#define NH 8
#define DHD 32

// weight K-slice split: Kt 0..RKT-1 in VGPRs(ish), Kt RKT..7 in LDS
#define RKT 5
#define LKT 3

// workspace offsets (float/uint granular)
#define OFF_GI     0u            // 4096*768 f32
#define OFF_GIBAR  3145728u      // 4096*768 f32
#define OFF_HEND   6291456u      // 4096*256 f32
#define OFF_GALL   7340032u      // 4096*256 f32
#define OFF_KMAT   8388608u      // 4096*256 f32
#define OFF_WFN    9437184u      // 98304 uints: gru Whh_note B-frags
#define OFF_WFB    9535488u      // 98304 uints: gru Whh_bar B-frags
#define OFF_WFIHN  9633792u      // 196608 uints: Wih_note B-frags (Kt=16)
#define OFF_WFIHB  9830400u      // 98304 uints: Wih_bar B-frags (Kt=8)
#define OFF_INT_BYTES 39714816u  // ints after floats/uints

#define OUT_FINAL 4096
#define OUT_CARR  5120

typedef __attribute__((ext_vector_type(8))) short short8v;  // 8 bf16 (4 VGPR)
typedef __attribute__((ext_vector_type(4))) float f32x4;

__device__ __forceinline__ unsigned int bf16rne(float f) {
    unsigned int u = __float_as_uint(f);
    return (u + 0x7fffu + ((u >> 16) & 1u)) >> 16;
}

// ---------- K0: mask dtype detection + per-batch scan + flattened segment list ----------
__global__ __launch_bounds__(256) void k_scan(const unsigned char* __restrict__ mraw,
        int* __restrict__ pos, int* __restrict__ lastk, int* __restrict__ nmask,
        int* __restrict__ sS, int* __restrict__ sLen, int* __restrict__ sC,
        int* __restrict__ nseg) {
    __shared__ int rnz[8];
    __shared__ int gt1;
    __shared__ int mode;
    __shared__ int snm[NB];
    int tid = threadIdx.x;
    if (tid < 8) rnz[tid] = 0;
    if (tid == 0) gt1 = 0;
    __syncthreads();
    for (int i = tid; i < NB * SEQ; i += 256) {
        unsigned char v = mraw[i];
        if (v) {
            rnz[i & 7] = 1;          // benign same-value race
            if (v > 1) gt1 = 1;
        }
    }
    __syncthreads();
    if (tid == 0) {
        bool lowhalf = rnz[0] | rnz[1] | rnz[4] | rnz[5];
        bool hihalf  = rnz[2] | rnz[3] | rnz[6] | rnz[7];
        int m;
        if (hihalf && !lowhalf) {
            m = (rnz[2] | rnz[3]) ? 3 : 4;          // f32 : f64
        } else if (gt1) {
            m = 5;                                   // 16-bit float-ish
        } else if (rnz[1] | rnz[3] | rnz[5] | rnz[7]) {
            m = 0;                                   // u8 bool
        } else if (rnz[4]) {
            m = 1;                                   // i32
        } else if (rnz[0]) {
            m = 2;                                   // i64
        } else {
            m = 0;
        }
        mode = m;
    }
    __syncthreads();
    if (tid < NB) {
        int b = tid;
        int cnt = 0;
        for (int t = 0; t < SEQ; ++t) {
            int idx = b * SEQ + t;
            int mv;
            switch (mode) {
                case 0:  mv = mraw[idx] != 0; break;
                case 1:  mv = ((const int*)mraw)[idx] != 0; break;
                case 2:  mv = ((const long long*)mraw)[idx] != 0LL; break;
                case 3:  mv = ((const float*)mraw)[idx] != 0.f; break;
                case 4:  mv = ((const double*)mraw)[idx] != 0.0; break;
                default: mv = ((const unsigned short*)mraw)[idx] != 0; break;
            }
            if (mv) { pos[b * SEQ + cnt] = t; ++cnt; }
            lastk[idx] = cnt - 1;
        }
        nmask[b] = cnt;
        snm[b] = cnt;
    }
    __syncthreads();
    if (tid < NB) {
        int b = tid;
        int base = 0;
        for (int x = 0; x < b; ++x) base += snm[x];
        int cnt = snm[b];
        for (int k = 0; k < cnt; ++k) {
            int e = pos[b * SEQ + k];
            int s = (k == 0) ? 0 : (pos[b * SEQ + k - 1] + 1);
            sS[base + k]   = b * SEQ + s;     // global gi row of first step
            sLen[base + k] = e - s;           // number of GRU steps
            sC[base + k]   = b * SEQ + k;     // chain id (hend row)
        }
    }
    __syncthreads();
    if (tid == 0) {
        int t = 0;
        for (int x = 0; x < NB; ++x) t += snm[x];
        *nseg = t;
    }
}

// ---------- pack W (768 x Kdim f32) into MFMA B-fragment order (bf16), Kt chunks of 32 ----------
// frag idx4 = (T*KTN + Kt)*64 + lane ; holds W[16T + (lane&15)][32Kt + (lane>>4)*8 + 0..7]
__global__ __launch_bounds__(256) void k_wfrag(const float* __restrict__ W, uint4* __restrict__ out,
                                               int Kdim, int KTN) {
    int idx = blockIdx.x * 256 + threadIdx.x;
    if (idx >= 48 * KTN * 64) return;
    int lane = idx & 63;
    int TK = idx >> 6;
    int T = TK / KTN, Kt = TK % KTN;
    int row = 16 * T + (lane & 15);
    int kb = 32 * Kt + (lane >> 4) * 8;
    const float* wr = W + (size_t)row * Kdim + kb;
    uint4 u;
    u.x = bf16rne(wr[0]) | (bf16rne(wr[1]) << 16);
    u.y = bf16rne(wr[2]) | (bf16rne(wr[3]) << 16);
    u.z = bf16rne(wr[4]) | (bf16rne(wr[5]) << 16);
    u.w = bf16rne(wr[6]) | (bf16rne(wr[7]) << 16);
    out[idx] = u;
}

// ---------- MFMA GEMM: C[m][n] = bias[n] + sum_k A[m][k] * W[n][k]  (A fp32, W pre-fragged bf16) ----------
// M x 768, Kdim in {512, 256}. Block = 64x64 tile, 256 thr / 4 waves; wave w -> row-tile w, nt=0..3.
__global__ __launch_bounds__(256) void k_gemm_mfma(int Kdim, int KTN,
        const float* __restrict__ A, const uint4* __restrict__ Bf,
        const float* __restrict__ bias, float* __restrict__ C) {
    int bm = blockIdx.x * 64, bn = blockIdx.y * 64;
    int tid = threadIdx.x;
    int w = tid >> 6;
    int lane = tid & 63;
    int arow = bm + 16 * w + (lane & 15);
    int kofs = (lane >> 4) * 8;
    f32x4 acc[4];
#pragma unroll
    for (int nt = 0; nt < 4; ++nt) acc[nt] = (f32x4){0.f, 0.f, 0.f, 0.f};
    for (int kc = 0; kc < KTN; ++kc) {
        const float* ap = A + (size_t)arow * Kdim + kc * 32 + kofs;
        float4 p0 = *reinterpret_cast<const float4*>(ap);
        float4 p1 = *reinterpret_cast<const float4*>(ap + 4);
        uint4 au;
        au.x = bf16rne(p0.x) | (bf16rne(p0.y) << 16);
        au.y = bf16rne(p0.z) | (bf16rne(p0.w) << 16);
        au.z = bf16rne(p1.x) | (bf16rne(p1.y) << 16);
        au.w = bf16rne(p1.z) | (bf16rne(p1.w) << 16);
        short8v a = __builtin_bit_cast(short8v, au);
#pragma unroll
        for (int nt = 0; nt < 4; ++nt) {
            int T = (bn >> 4) + nt;
            uint4 u = Bf[(size_t)(T * KTN + kc) * 64 + lane];
            short8v bv = __builtin_bit_cast(short8v, u);
            acc[nt] = __builtin_amdgcn_mfma_f32_16x16x32_bf16(a, bv, acc[nt], 0, 0, 0);
        }
    }
    int crow = bm + 16 * w + (lane >> 4) * 4;
#pragma unroll
    for (int nt = 0; nt < 4; ++nt) {
        int col = bn + 16 * nt + (lane & 15);
        float bv = bias[col];
#pragma unroll
        for (int r = 0; r < 4; ++r)
            C[(size_t)(crow + r) * G3 + col] = acc[nt][r] + bv;
    }
}

// ---------- K matrix: pooled onset + sinusoidal PE, project 32->256 ----------
__global__ __launch_bounds__(64) void k_keys(const float* __restrict__ onset,
        const float* __restrict__ Wk, const float* __restrict__ bk, float* __restrict__ Kmat) {
    int bt = blockIdx.x;
    int b = bt >> 10, t = bt & 1023;
    __shared__ float xin[CO];
    int tid = threadIdx.x;
    if (tid < CO) {
        float s = 0.f;
        const float* base = onset + ((size_t)b * TONS + (size_t)t * POOLN) * CO + tid;
#pragma unroll
        for (int p = 0; p < POOLN; ++p) s += base[p * CO];
        s *= (1.f / POOLN);
        int j = tid >> 1;
        float dv = expf(-logf(10000.f) * (float)j / 16.f);
        float ang = (float)t * dv;
        s += (tid & 1) ? cosf(ang) : sinf(ang);
        xin[tid] = s;
    }
    __syncthreads();
    for (int n = tid; n < DB; n += 64) {
        float acc = bk[n];
        const float* wr = Wk + (size_t)n * CO;
#pragma unroll
        for (int c = 0; c < CO; ++c) acc += xin[c] * wr[c];
        Kmat[(size_t)bt * DB + n] = acc;
    }
}

// ---------- MFMA-batched GRU, hybrid reg+LDS weight residency (round-9 schedule) ----------
// 16 segments per block; gh(16x768) = H(16x256) @ Whh^T per step.
// 512 thr = 8 waves; wave w owns tiles t=0..5 (t=2g+ii -> T=16g+2w+ii).
template<int MODE>
__global__ __launch_bounds__(512, 1) void k_gru(
        const uint4* __restrict__ wf, const float* __restrict__ bhh,
        const float* __restrict__ gx_src,
        const int* __restrict__ sS, const int* __restrict__ sLen,
        const int* __restrict__ sC, const int* __restrict__ nseg_p,
        const int* __restrict__ nmask, float* __restrict__ outp) {
    int bg = blockIdx.x;
    int nseg = (MODE == 0) ? *nseg_p : NB;
    if (16 * bg >= nseg) return;
    int tid = threadIdx.x;
    int w = tid >> 6;
    int lane = tid & 63;
    int lhi = lane >> 4, c = lane & 15;

    __shared__ __align__(16) unsigned short hfrag[8 * 64 * 8];           // 8 KB, A-frag layout
    __shared__ __align__(16) uint4 wlds[8 * 6 * LKT * 64];               // 147 KB, B-frag slices

    // one-time weight residency load
    uint4 wreg[6][RKT];
#pragma unroll
    for (int t = 0; t < 6; ++t) {
        int T = 16 * (t >> 1) + 2 * w + (t & 1);
#pragma unroll
        for (int kt = 0; kt < RKT; ++kt)
            wreg[t][kt] = wf[(size_t)(T * 8 + kt) * 64 + lane];
#pragma unroll
        for (int kt = 0; kt < LKT; ++kt)
            wlds[((w * 6 + t) * LKT + kt) * 64 + lane] = wf[(size_t)(T * 8 + RKT + kt) * 64 + lane];
    }

    int ss_r[4], len_r[4], sc_r[4];
#pragma unroll
    for (int r = 0; r < 4; ++r) {
        int m = 4 * lhi + r;
        int gs = 16 * bg + m;
        if (MODE == 0) {
            bool v = gs < nseg;
            ss_r[r]  = v ? sS[gs] : 0;
            len_r[r] = v ? sLen[gs] : 0;
            sc_r[r]  = v ? sC[gs] : 0;
        } else {
            bool v = m < NB;
            ss_r[r]  = v ? m * SEQ : 0;
            len_r[r] = v ? nmask[m] : 0;
            sc_r[r]  = 0;
        }
    }
    int mx = 0;
    for (int q = 0; q < 16; ++q) {
        int gs = 16 * bg + q;
        int L = (MODE == 0) ? ((gs < nseg) ? sLen[gs] : 0)
                            : ((q < NB) ? nmask[q] : 0);
        mx = max(mx, L);
    }
    float bh[3][2];
#pragma unroll
    for (int g = 0; g < 3; ++g)
#pragma unroll
        for (int ii = 0; ii < 2; ++ii)
            bh[g][ii] = bhh[g * 256 + 32 * w + 16 * ii + c];
    float h[4][2] = {};

    for (int i = 0; i < mx; ++i) {
        // gx gather for this step
        float gx[3][2][4];
#pragma unroll
        for (int r = 0; r < 4; ++r) {
            int row = (i < len_r[r]) ? (ss_r[r] + i) : ss_r[r];
            const float* gp = gx_src + (size_t)row * G3 + 32 * w + c;
#pragma unroll
            for (int g = 0; g < 3; ++g)
#pragma unroll
                for (int ii = 0; ii < 2; ++ii)
                    gx[g][ii][r] = gp[g * 256 + 16 * ii];
        }
        f32x4 acc[6];
#pragma unroll
        for (int t = 0; t < 6; ++t) acc[t] = (f32x4){0.f, 0.f, 0.f, 0.f};
        if (i > 0) {
            const short8v* hf8 = (const short8v*)hfrag;
#pragma unroll
            for (int kt = 0; kt < 8; ++kt) {
                short8v a = hf8[kt * 64 + lane];
                if (kt < RKT) {
#pragma unroll
                    for (int t = 0; t < 6; ++t) {
                        short8v bv = __builtin_bit_cast(short8v, wreg[t][kt]);
                        acc[t] = __builtin_amdgcn_mfma_f32_16x16x32_bf16(a, bv, acc[t], 0, 0, 0);
                    }
                } else {
#pragma unroll
                    for (int t = 0; t < 6; ++t) {
                        uint4 u = wlds[((w * 6 + t) * LKT + (kt - RKT)) * 64 + lane];
                        short8v bv = __builtin_bit_cast(short8v, u);
                        acc[t] = __builtin_amdgcn_mfma_f32_16x16x32_bf16(a, bv, acc[t], 0, 0, 0);
                    }
                }
            }
        }
        // gate math; D layout: m=(lane>>4)*4+r at vector elem r, col=lane&15; tile t=2g+ii
#pragma unroll
        for (int r = 0; r < 4; ++r) {
#pragma unroll
            for (int ii = 0; ii < 2; ++ii) {
                float rr = 1.f / (1.f + expf(-(gx[0][ii][r] + bh[0][ii] + acc[0 + ii][r])));
                float zz = 1.f / (1.f + expf(-(gx[1][ii][r] + bh[1][ii] + acc[2 + ii][r])));
                float nn = tanhf(gx[2][ii][r] + rr * (bh[2][ii] + acc[4 + ii][r]));
                float hv = (1.f - zz) * nn + zz * h[r][ii];
                bool act = i < len_r[r];
                hv = act ? hv : h[r][ii];
                h[r][ii] = hv;
                if (MODE == 1) {
                    if (lhi == 0 && act) {   // m = r < NB
                        int j = 32 * w + 16 * ii + c;
                        outp[(size_t)(ss_r[r] + i) * DB + j] = hv;
                    }
                }
            }
        }
        __syncthreads();   // all a-frag/wlds reads done before hfrag rewrite
#pragma unroll
        for (int r = 0; r < 4; ++r)
#pragma unroll
            for (int ii = 0; ii < 2; ++ii) {
                int j = 32 * w + 16 * ii + c;        // j>>5 == w
                int m = 4 * lhi + r;
                int lp = m + 16 * ((j >> 3) & 3);
                hfrag[(size_t)(w * 64 + lp) * 8 + (j & 7)] = (unsigned short)bf16rne(h[r][ii]);
            }
        __syncthreads();   // writes visible for next step
    }
    if (MODE == 0) {
#pragma unroll
        for (int r = 0; r < 4; ++r) {
            int gs = 16 * bg + 4 * lhi + r;
            if (gs < nseg) {
#pragma unroll
                for (int ii = 0; ii < 2; ++ii)
                    outp[(size_t)sc_r[r] * DB + 32 * w + 16 * ii + c] = h[r][ii];
            }
        }
    }
}

// ---------- fill outputs: h_bar_carried, h_bar_final, zero com ----------
__global__ __launch_bounds__(256) void k_fill(const float* __restrict__ gall,
        const int* __restrict__ lastk, const int* __restrict__ nmask,
        float* __restrict__ out) {
    int bt = blockIdx.x;
    int b = bt >> 10, t = bt & 1023;
    int tid = threadIdx.x;
    int lk = lastk[bt];
    float v = (lk >= 0) ? gall[((size_t)b * SEQ + lk) * DB + tid] : 0.f;
    out[OUT_CARR + (size_t)bt * DB + tid] = v;
    if (tid == 0) out[bt] = 0.f;
    if (t == 0) {
        int nm = nmask[b];
        float fv = (nm > 0) ? gall[((size_t)b * SEQ + nm - 1) * DB + tid] : 0.f;
        out[OUT_FINAL + b * DB + tid] = fv;
    }
}

// ---------- attention + com at mask rows only ----------
__global__ __launch_bounds__(256) void k_attn(const float* __restrict__ gall,
        const float* __restrict__ Wq, const float* __restrict__ bq,
        const float* __restrict__ Kmat, const int* __restrict__ pos,
        const int* __restrict__ nmask, const float* __restrict__ pbs_ptr,
        float* __restrict__ out) {
    int c = blockIdx.x;
    int b = c >> 10, k = c & 1023;
    if (k >= nmask[b]) return;
    int trow = pos[b * SEQ + k];
    __shared__ float q[DB];
    __shared__ float grow[DB];
    __shared__ float sc[NH][TOCT];
    __shared__ float comh[NH];
    int tid = threadIdx.x;
    grow[tid] = gall[((size_t)b * SEQ + k) * DB + tid];
    __syncthreads();
    {
        float acc = bq[tid];
        const float* wr = Wq + (size_t)tid * DB;
#pragma unroll 4
        for (int j = 0; j < DB; ++j) acc += grow[j] * wr[j];
        q[tid] = acc;
    }
    __syncthreads();
    float pbs = *pbs_ptr;
    const float scale = 0.17677669529663687f; // 1/sqrt(32)
    for (int t = tid; t < TOCT; t += 256) {
        const float* kr = Kmat + ((size_t)b * TOCT + t) * DB;
        float tp = (float)t * (1.f / 1023.f);
#pragma unroll
        for (int h = 0; h < NH; ++h) {
            float acc = 0.f;
#pragma unroll
            for (int d = 0; d < DHD; ++d) acc += q[h * DHD + d] * kr[h * DHD + d];
            sc[h][t] = acc * scale - pbs * tp;
        }
    }
    __syncthreads();
    int hh = tid >> 5, l = tid & 31;
    float mx = -1e30f;
    for (int t = l; t < TOCT; t += 32) mx = fmaxf(mx, sc[hh][t]);
#pragma unroll
    for (int o = 16; o > 0; o >>= 1) mx = fmaxf(mx, __shfl_xor(mx, o, 32));
    float se = 0.f, sw = 0.f;
    for (int t = l; t < TOCT; t += 32) {
        float e = expf(sc[hh][t] - mx);
        se += e;
        sw += e * ((float)t * (1.f / 1023.f));
    }
#pragma unroll
    for (int o = 16; o > 0; o >>= 1) { se += __shfl_xor(se, o, 32); sw += __shfl_xor(sw, o, 32); }
    if (l == 0) comh[hh] = sw / se;
    __syncthreads();
    if (tid == 0) {
        float cm = 0.f;
#pragma unroll
        for (int h = 0; h < NH; ++h) cm += comh[h];
        out[b * SEQ + trow] = cm * (1.f / NH);
    }
}

extern "C" void kernel_launch(void* const* d_in, const int* in_sizes, int n_in,
                              void* d_out, int out_size, void* d_ws, size_t ws_size,
                              hipStream_t stream) {
    const float* te    = (const float*)d_in[0];
    const float* onset = (const float*)d_in[1];
    const unsigned char* mask = (const unsigned char*)d_in[2];
    const float* Wih_n = (const float*)d_in[3];
    const float* Whh_n = (const float*)d_in[4];
    const float* bih_n = (const float*)d_in[5];
    const float* bhh_n = (const float*)d_in[6];
    const float* Wih_b = (const float*)d_in[7];
    const float* Whh_b = (const float*)d_in[8];
    const float* bih_b = (const float*)d_in[9];
    const float* bhh_b = (const float*)d_in[10];
    const float* Wq    = (const float*)d_in[11];
    const float* bq    = (const float*)d_in[12];
    const float* Wk    = (const float*)d_in[13];
    const float* bk    = (const float*)d_in[14];
    const float* pbs   = (const float*)d_in[15];
    float* out = (float*)d_out;

    float* ws    = (float*)d_ws;
    float* gi    = ws + OFF_GI;
    float* gibar = ws + OFF_GIBAR;
    float* hend  = ws + OFF_HEND;
    float* gall  = ws + OFF_GALL;
    float* kmat  = ws + OFF_KMAT;
    uint4* wfn   = (uint4*)(ws + OFF_WFN);
    uint4* wfb   = (uint4*)(ws + OFF_WFB);
    uint4* wfihn = (uint4*)(ws + OFF_WFIHN);
    uint4* wfihb = (uint4*)(ws + OFF_WFIHB);
    int* ipos    = (int*)((char*)d_ws + OFF_INT_BYTES);
    int* ilastk  = ipos + NB * SEQ;
    int* inmask  = ilastk + NB * SEQ;
    int* isS     = inmask + NB;
    int* isLen   = isS + NB * SEQ;
    int* isC     = isLen + NB * SEQ;
    int* inseg   = isC + NB * SEQ;

    k_scan<<<1, 256, 0, stream>>>(mask, ipos, ilastk, inmask, isS, isLen, isC, inseg);
    k_wfrag<<<96, 256, 0, stream>>>(Whh_n, wfn, DB, 8);
    k_wfrag<<<96, 256, 0, stream>>>(Whh_b, wfb, DB, 8);
    k_wfrag<<<192, 256, 0, stream>>>(Wih_n, wfihn, DM, 16);
    k_wfrag<<<96, 256, 0, stream>>>(Wih_b, wfihb, DB, 8);
    k_keys<<<NB * TOCT, 64, 0, stream>>>(onset, Wk, bk, kmat);
    k_gemm_mfma<<<dim3(64, 12), 256, 0, stream>>>(DM, 16, te, wfihn, bih_n, gi);
    k_gru<0><<<256, 512, 0, stream>>>(wfn, bhh_n, gi, isS, isLen, isC, inseg, inmask, hend);
    k_gemm_mfma<<<dim3(64, 12), 256, 0, stream>>>(DB, 8, hend, wfihb, bih_b, gibar);
    k_gru<1><<<1, 512, 0, stream>>>(wfb, bhh_b, gibar, isS, isLen, isC, inseg, inmask, gall);
    k_fill<<<NB * SEQ, 256, 0, stream>>>(gall, ilastk, inmask, out);
    k_attn<<<NB * SEQ, 256, 0, stream>>>(gall, Wq, bq, kmat, ipos, inmask, pbs, out);
}

// Round 12
// 941.493 us; speedup vs baseline: 1.2516x; 1.0422x over previous
//
#include <hip/hip_runtime.h>
#include <hip/hip_bf16.h>
#include <math.h>

#define NB 4
#define SEQ 1024
#define DM 512
#define DB 256
#define G3 768
#define CO 32
#define TONS 8192
#define POOLN 8
#define TOCT 1024
#define NH 8
#define DHD 32

// weight K-slice split: Kt 0..RKT-1 reloaded from L2, Kt RKT..7 in LDS
#define RKT 5
#define LKT 3

// workspace offsets (float/uint granular)
#define OFF_GI     0u            // 4096*768 f32
#define OFF_GIBAR  3145728u      // 4096*768 f32
#define OFF_HEND   6291456u      // 4096*256 f32
#define OFF_GALL   7340032u      // 4096*256 f32
#define OFF_KMAT   8388608u      // 4096*256 f32
#define OFF_WFN    9437184u      // 98304 uints: gru Whh_note B-frags
#define OFF_WFB    9535488u      // 98304 uints: gru Whh_bar B-frags
#define OFF_WFIHN  9633792u      // 196608 uints: Wih_note B-frags (Kt=16)
#define OFF_WFIHB  9830400u      // 98304 uints: Wih_bar B-frags (Kt=8)
#define OFF_INT_BYTES 39714816u  // ints after floats/uints

#define OUT_FINAL 4096
#define OUT_CARR  5120

typedef __attribute__((ext_vector_type(8))) short short8v;  // 8 bf16 (4 VGPR)
typedef __attribute__((ext_vector_type(4))) float f32x4;

__device__ __forceinline__ unsigned int bf16rne(float f) {
    unsigned int u = __float_as_uint(f);
    return (u + 0x7fffu + ((u >> 16) & 1u)) >> 16;
}
__device__ __forceinline__ float fsigm(float x) {
    return __fdividef(1.f, 1.f + __expf(-x));
}
__device__ __forceinline__ float ftanh(float x) {
    return 1.f - __fdividef(2.f, __expf(2.f * x) + 1.f);
}

// ---------- K0: mask dtype detection + per-batch scan + flattened segment list ----------
__global__ __launch_bounds__(256) void k_scan(const unsigned char* __restrict__ mraw,
        int* __restrict__ pos, int* __restrict__ lastk, int* __restrict__ nmask,
        int* __restrict__ sS, int* __restrict__ sLen, int* __restrict__ sC,
        int* __restrict__ nseg) {
    __shared__ int rnz[8];
    __shared__ int gt1;
    __shared__ int mode;
    __shared__ int snm[NB];
    int tid = threadIdx.x;
    if (tid < 8) rnz[tid] = 0;
    if (tid == 0) gt1 = 0;
    __syncthreads();
    for (int i = tid; i < NB * SEQ; i += 256) {
        unsigned char v = mraw[i];
        if (v) {
            rnz[i & 7] = 1;          // benign same-value race
            if (v > 1) gt1 = 1;
        }
    }
    __syncthreads();
    if (tid == 0) {
        bool lowhalf = rnz[0] | rnz[1] | rnz[4] | rnz[5];
        bool hihalf  = rnz[2] | rnz[3] | rnz[6] | rnz[7];
        int m;
        if (hihalf && !lowhalf) {
            m = (rnz[2] | rnz[3]) ? 3 : 4;          // f32 : f64
        } else if (gt1) {
            m = 5;                                   // 16-bit float-ish
        } else if (rnz[1] | rnz[3] | rnz[5] | rnz[7]) {
            m = 0;                                   // u8 bool
        } else if (rnz[4]) {
            m = 1;                                   // i32
        } else if (rnz[0]) {
            m = 2;                                   // i64
        } else {
            m = 0;
        }
        mode = m;
    }
    __syncthreads();
    if (tid < NB) {
        int b = tid;
        int cnt = 0;
        for (int t = 0; t < SEQ; ++t) {
            int idx = b * SEQ + t;
            int mv;
            switch (mode) {
                case 0:  mv = mraw[idx] != 0; break;
                case 1:  mv = ((const int*)mraw)[idx] != 0; break;
                case 2:  mv = ((const long long*)mraw)[idx] != 0LL; break;
                case 3:  mv = ((const float*)mraw)[idx] != 0.f; break;
                case 4:  mv = ((const double*)mraw)[idx] != 0.0; break;
                default: mv = ((const unsigned short*)mraw)[idx] != 0; break;
            }
            if (mv) { pos[b * SEQ + cnt] = t; ++cnt; }
            lastk[idx] = cnt - 1;
        }
        nmask[b] = cnt;
        snm[b] = cnt;
    }
    __syncthreads();
    if (tid < NB) {
        int b = tid;
        int base = 0;
        for (int x = 0; x < b; ++x) base += snm[x];
        int cnt = snm[b];
        for (int k = 0; k < cnt; ++k) {
            int e = pos[b * SEQ + k];
            int s = (k == 0) ? 0 : (pos[b * SEQ + k - 1] + 1);
            sS[base + k]   = b * SEQ + s;     // global gi row of first step
            sLen[base + k] = e - s;           // number of GRU steps
            sC[base + k]   = b * SEQ + k;     // chain id (hend row)
        }
    }
    __syncthreads();
    if (tid == 0) {
        int t = 0;
        for (int x = 0; x < NB; ++x) t += snm[x];
        *nseg = t;
    }
}

// ---------- pack W (768 x Kdim f32) into MFMA B-fragment order (bf16), Kt chunks of 32 ----------
__global__ __launch_bounds__(256) void k_wfrag(const float* __restrict__ W, uint4* __restrict__ out,
                                               int Kdim, int KTN) {
    int idx = blockIdx.x * 256 + threadIdx.x;
    if (idx >= 48 * KTN * 64) return;
    int lane = idx & 63;
    int TK = idx >> 6;
    int T = TK / KTN, Kt = TK % KTN;
    int row = 16 * T + (lane & 15);
    int kb = 32 * Kt + (lane >> 4) * 8;
    const float* wr = W + (size_t)row * Kdim + kb;
    uint4 u;
    u.x = bf16rne(wr[0]) | (bf16rne(wr[1]) << 16);
    u.y = bf16rne(wr[2]) | (bf16rne(wr[3]) << 16);
    u.z = bf16rne(wr[4]) | (bf16rne(wr[5]) << 16);
    u.w = bf16rne(wr[6]) | (bf16rne(wr[7]) << 16);
    out[idx] = u;
}

// ---------- MFMA GEMM: C[m][n] = bias[n] + sum_k A[m][k] * W[n][k] ----------
// LIM: skip row-blocks beyond nmask[b] (gibar only needs first nm rows per batch stripe)
template<bool LIM>
__global__ __launch_bounds__(256) void k_gemm_mfma(int Kdim, int KTN,
        const float* __restrict__ A, const uint4* __restrict__ Bf,
        const float* __restrict__ bias, float* __restrict__ C,
        const int* __restrict__ nmask) {
    int bm = blockIdx.x * 64, bn = blockIdx.y * 64;
    if (LIM) {
        int b = bm >> 10;
        if ((bm & 1023) >= nmask[b]) return;
    }
    int tid = threadIdx.x;
    int w = tid >> 6;
    int lane = tid & 63;
    int arow = bm + 16 * w + (lane & 15);
    int kofs = (lane >> 4) * 8;
    f32x4 acc[4];
#pragma unroll
    for (int nt = 0; nt < 4; ++nt) acc[nt] = (f32x4){0.f, 0.f, 0.f, 0.f};
    for (int kc = 0; kc < KTN; ++kc) {
        const float* ap = A + (size_t)arow * Kdim + kc * 32 + kofs;
        float4 p0 = *reinterpret_cast<const float4*>(ap);
        float4 p1 = *reinterpret_cast<const float4*>(ap + 4);
        uint4 au;
        au.x = bf16rne(p0.x) | (bf16rne(p0.y) << 16);
        au.y = bf16rne(p0.z) | (bf16rne(p0.w) << 16);
        au.z = bf16rne(p1.x) | (bf16rne(p1.y) << 16);
        au.w = bf16rne(p1.z) | (bf16rne(p1.w) << 16);
        short8v a = __builtin_bit_cast(short8v, au);
#pragma unroll
        for (int nt = 0; nt < 4; ++nt) {
            int T = (bn >> 4) + nt;
            uint4 u = Bf[(size_t)(T * KTN + kc) * 64 + lane];
            short8v bv = __builtin_bit_cast(short8v, u);
            acc[nt] = __builtin_amdgcn_mfma_f32_16x16x32_bf16(a, bv, acc[nt], 0, 0, 0);
        }
    }
    int crow = bm + 16 * w + (lane >> 4) * 4;
#pragma unroll
    for (int nt = 0; nt < 4; ++nt) {
        int col = bn + 16 * nt + (lane & 15);
        float bv = bias[col];
#pragma unroll
        for (int r = 0; r < 4; ++r)
            C[(size_t)(crow + r) * G3 + col] = acc[nt][r] + bv;
    }
}

// ---------- K matrix: pooled onset + sinusoidal PE, project 32->256 ----------
__global__ __launch_bounds__(64) void k_keys(const float* __restrict__ onset,
        const float* __restrict__ Wk, const float* __restrict__ bk, float* __restrict__ Kmat) {
    int bt = blockIdx.x;
    int b = bt >> 10, t = bt & 1023;
    __shared__ float xin[CO];
    int tid = threadIdx.x;
    if (tid < CO) {
        float s = 0.f;
        const float* base = onset + ((size_t)b * TONS + (size_t)t * POOLN) * CO + tid;
#pragma unroll
        for (int p = 0; p < POOLN; ++p) s += base[p * CO];
        s *= (1.f / POOLN);
        int j = tid >> 1;
        float dv = expf(-logf(10000.f) * (float)j / 16.f);
        float ang = (float)t * dv;
        s += (tid & 1) ? cosf(ang) : sinf(ang);
        xin[tid] = s;
    }
    __syncthreads();
    for (int n = tid; n < DB; n += 64) {
        float acc = bk[n];
        const float* wr = Wk + (size_t)n * CO;
#pragma unroll
        for (int c = 0; c < CO; ++c) acc += xin[c] * wr[c];
        Kmat[(size_t)bt * DB + n] = acc;
    }
}

// ---------- MFMA-batched GRU: round-9 structure + fast gates + gx prefetch (2x unroll) ----------
template<int MODE>
__global__ __launch_bounds__(512, 1) void k_gru(
        const uint4* __restrict__ wf, const float* __restrict__ bhh,
        const float* __restrict__ gx_src,
        const int* __restrict__ sS, const int* __restrict__ sLen,
        const int* __restrict__ sC, const int* __restrict__ nseg_p,
        const int* __restrict__ nmask, float* __restrict__ outp) {
    int bg = blockIdx.x;
    int nseg = (MODE == 0) ? *nseg_p : NB;
    if (16 * bg >= nseg) return;
    int tid = threadIdx.x;
    int w = tid >> 6;
    int lane = tid & 63;
    int lhi = lane >> 4, c = lane & 15;

    __shared__ __align__(16) unsigned short hfrag[8 * 64 * 8];           // 8 KB, A-frag layout
    __shared__ __align__(16) uint4 wlds[8 * 6 * LKT * 64];               // 147 KB, B-frag slices

    uint4 wreg[6][RKT];
#pragma unroll
    for (int t = 0; t < 6; ++t) {
        int T = 16 * (t >> 1) + 2 * w + (t & 1);
#pragma unroll
        for (int kt = 0; kt < RKT; ++kt)
            wreg[t][kt] = wf[(size_t)(T * 8 + kt) * 64 + lane];
#pragma unroll
        for (int kt = 0; kt < LKT; ++kt)
            wlds[((w * 6 + t) * LKT + kt) * 64 + lane] = wf[(size_t)(T * 8 + RKT + kt) * 64 + lane];
    }

    int ss_r[4], len_r[4], sc_r[4];
#pragma unroll
    for (int r = 0; r < 4; ++r) {
        int m = 4 * lhi + r;
        int gs = 16 * bg + m;
        if (MODE == 0) {
            bool v = gs < nseg;
            ss_r[r]  = v ? sS[gs] : 0;
            len_r[r] = v ? sLen[gs] : 0;
            sc_r[r]  = v ? sC[gs] : 0;
        } else {
            bool v = m < NB;
            ss_r[r]  = v ? m * SEQ : 0;
            len_r[r] = v ? nmask[m] : 0;
            sc_r[r]  = 0;
        }
    }
    int mx = 0;
    for (int q = 0; q < 16; ++q) {
        int gs = 16 * bg + q;
        int L = (MODE == 0) ? ((gs < nseg) ? sLen[gs] : 0)
                            : ((q < NB) ? nmask[q] : 0);
        mx = max(mx, L);
    }
    float bh[3][2];
#pragma unroll
    for (int g = 0; g < 3; ++g)
#pragma unroll
        for (int ii = 0; ii < 2; ++ii)
            bh[g][ii] = bhh[g * 256 + 32 * w + 16 * ii + c];
    float h[4][2] = {};

#define LOADGX(dst, step)                                                        \
    {                                                                            \
        int i_ = (step);                                                         \
        _Pragma("unroll")                                                        \
        for (int r = 0; r < 4; ++r) {                                            \
            int row = (i_ < len_r[r]) ? (ss_r[r] + i_) : ss_r[r];                \
            const float* gp = gx_src + (size_t)row * G3 + 32 * w + c;            \
            _Pragma("unroll")                                                    \
            for (int g = 0; g < 3; ++g)                                          \
                _Pragma("unroll")                                                \
                for (int ii = 0; ii < 2; ++ii)                                   \
                    dst[g][ii][r] = gp[g * 256 + 16 * ii];                       \
        }                                                                        \
    }

#define GRU_STEP(I, GX)                                                          \
    {                                                                            \
        int i_ = (I);                                                            \
        f32x4 acc[6];                                                            \
        _Pragma("unroll")                                                        \
        for (int t = 0; t < 6; ++t) acc[t] = (f32x4){0.f, 0.f, 0.f, 0.f};        \
        if (i_ > 0) {                                                            \
            const short8v* hf8 = (const short8v*)hfrag;                          \
            _Pragma("unroll")                                                    \
            for (int kt = 0; kt < 8; ++kt) {                                     \
                short8v a = hf8[kt * 64 + lane];                                 \
                if (kt < RKT) {                                                  \
                    _Pragma("unroll")                                            \
                    for (int t = 0; t < 6; ++t) {                                \
                        short8v bv = __builtin_bit_cast(short8v, wreg[t][kt]);   \
                        acc[t] = __builtin_amdgcn_mfma_f32_16x16x32_bf16(        \
                                a, bv, acc[t], 0, 0, 0);                         \
                    }                                                            \
                } else {                                                         \
                    _Pragma("unroll")                                            \
                    for (int t = 0; t < 6; ++t) {                                \
                        uint4 u = wlds[((w * 6 + t) * LKT + (kt - RKT)) * 64 + lane]; \
                        short8v bv = __builtin_bit_cast(short8v, u);             \
                        acc[t] = __builtin_amdgcn_mfma_f32_16x16x32_bf16(        \
                                a, bv, acc[t], 0, 0, 0);                         \
                    }                                                            \
                }                                                                \
            }                                                                    \
        }                                                                        \
        _Pragma("unroll")                                                        \
        for (int r = 0; r < 4; ++r) {                                            \
            _Pragma("unroll")                                                    \
            for (int ii = 0; ii < 2; ++ii) {                                     \
                float rr = fsigm(GX[0][ii][r] + bh[0][ii] + acc[0 + ii][r]);     \
                float zz = fsigm(GX[1][ii][r] + bh[1][ii] + acc[2 + ii][r]);     \
                float nn = ftanh(GX[2][ii][r] + rr * (bh[2][ii] + acc[4 + ii][r])); \
                float hv = (1.f - zz) * nn + zz * h[r][ii];                      \
                bool act = i_ < len_r[r];                                        \
                hv = act ? hv : h[r][ii];                                        \
                h[r][ii] = hv;                                                   \
                if (MODE == 1) {                                                 \
                    if (lhi == 0 && act) {                                       \
                        int j = 32 * w + 16 * ii + c;                            \
                        outp[(size_t)(ss_r[r] + i_) * DB + j] = hv;              \
                    }                                                            \
                }                                                                \
            }                                                                    \
        }                                                                        \
        __syncthreads();                                                         \
        _Pragma("unroll")                                                        \
        for (int r = 0; r < 4; ++r)                                              \
            _Pragma("unroll")                                                    \
            for (int ii = 0; ii < 2; ++ii) {                                     \
                int j = 32 * w + 16 * ii + c;                                    \
                int m = 4 * lhi + r;                                             \
                int lp = m + 16 * ((j >> 3) & 3);                                \
                hfrag[(size_t)(w * 64 + lp) * 8 + (j & 7)] =                     \
                    (unsigned short)bf16rne(h[r][ii]);                           \
            }                                                                    \
        __syncthreads();                                                         \
    }

    float gxa[3][2][4], gxb[3][2][4];
    LOADGX(gxa, 0)
    for (int i = 0; i < mx; i += 2) {
        LOADGX(gxb, i + 1)          // in flight during step i
        GRU_STEP(i, gxa)
        LOADGX(gxa, i + 2)          // in flight during step i+1
        GRU_STEP(i + 1, gxb)        // no-op semantics if i+1 >= lens
    }
#undef LOADGX
#undef GRU_STEP
    if (MODE == 0) {
#pragma unroll
        for (int r = 0; r < 4; ++r) {
            int gs = 16 * bg + 4 * lhi + r;
            if (gs < nseg) {
#pragma unroll
                for (int ii = 0; ii < 2; ++ii)
                    outp[(size_t)sc_r[r] * DB + 32 * w + 16 * ii + c] = h[r][ii];
            }
        }
    }
}

// ---------- fill outputs: h_bar_carried, h_bar_final, zero com ----------
__global__ __launch_bounds__(256) void k_fill(const float* __restrict__ gall,
        const int* __restrict__ lastk, const int* __restrict__ nmask,
        float* __restrict__ out) {
    int bt = blockIdx.x;
    int b = bt >> 10, t = bt & 1023;
    int tid = threadIdx.x;
    int lk = lastk[bt];
    float v = (lk >= 0) ? gall[((size_t)b * SEQ + lk) * DB + tid] : 0.f;
    out[OUT_CARR + (size_t)bt * DB + tid] = v;
    if (tid == 0) out[bt] = 0.f;
    if (t == 0) {
        int nm = nmask[b];
        float fv = (nm > 0) ? gall[((size_t)b * SEQ + nm - 1) * DB + tid] : 0.f;
        out[OUT_FINAL + b * DB + tid] = fv;
    }
}

// ---------- attention + com at mask rows only ----------
__global__ __launch_bounds__(256) void k_attn(const float* __restrict__ gall,
        const float* __restrict__ Wq, const float* __restrict__ bq,
        const float* __restrict__ Kmat, const int* __restrict__ pos,
        const int* __restrict__ nmask, const float* __restrict__ pbs_ptr,
        float* __restrict__ out) {
    int c = blockIdx.x;
    int b = c >> 10, k = c & 1023;
    if (k >= nmask[b]) return;
    int trow = pos[b * SEQ + k];
    __shared__ float q[DB];
    __shared__ float grow[DB];
    __shared__ float sc[NH][TOCT];
    __shared__ float comh[NH];
    int tid = threadIdx.x;
    grow[tid] = gall[((size_t)b * SEQ + k) * DB + tid];
    __syncthreads();
    {
        float acc = bq[tid];
        const float* wr = Wq + (size_t)tid * DB;
#pragma unroll 4
        for (int j = 0; j < DB; ++j) acc += grow[j] * wr[j];
        q[tid] = acc;
    }
    __syncthreads();
    float pbs = *pbs_ptr;
    const float scale = 0.17677669529663687f; // 1/sqrt(32)
    for (int t = tid; t < TOCT; t += 256) {
        const float* kr = Kmat + ((size_t)b * TOCT + t) * DB;
        float tp = (float)t * (1.f / 1023.f);
#pragma unroll
        for (int h = 0; h < NH; ++h) {
            float acc = 0.f;
#pragma unroll
            for (int d = 0; d < DHD; ++d) acc += q[h * DHD + d] * kr[h * DHD + d];
            sc[h][t] = acc * scale - pbs * tp;
        }
    }
    __syncthreads();
    int hh = tid >> 5, l = tid & 31;
    float mx = -1e30f;
    for (int t = l; t < TOCT; t += 32) mx = fmaxf(mx, sc[hh][t]);
#pragma unroll
    for (int o = 16; o > 0; o >>= 1) mx = fmaxf(mx, __shfl_xor(mx, o, 32));
    float se = 0.f, sw = 0.f;
    for (int t = l; t < TOCT; t += 32) {
        float e = __expf(sc[hh][t] - mx);
        se += e;
        sw += e * ((float)t * (1.f / 1023.f));
    }
#pragma unroll
    for (int o = 16; o > 0; o >>= 1) { se += __shfl_xor(se, o, 32); sw += __shfl_xor(sw, o, 32); }
    if (l == 0) comh[hh] = sw / se;
    __syncthreads();
    if (tid == 0) {
        float cm = 0.f;
#pragma unroll
        for (int h = 0; h < NH; ++h) cm += comh[h];
        out[b * SEQ + trow] = cm * (1.f / NH);
    }
}

extern "C" void kernel_launch(void* const* d_in, const int* in_sizes, int n_in,
                              void* d_out, int out_size, void* d_ws, size_t ws_size,
                              hipStream_t stream) {
    const float* te    = (const float*)d_in[0];
    const float* onset = (const float*)d_in[1];
    const unsigned char* mask = (const unsigned char*)d_in[2];
    const float* Wih_n = (const float*)d_in[3];
    const float* Whh_n = (const float*)d_in[4];
    const float* bih_n = (const float*)d_in[5];
    const float* bhh_n = (const float*)d_in[6];
    const float* Wih_b = (const float*)d_in[7];
    const float* Whh_b = (const float*)d_in[8];
    const float* bih_b = (const float*)d_in[9];
    const float* bhh_b = (const float*)d_in[10];
    const float* Wq    = (const float*)d_in[11];
    const float* bq    = (const float*)d_in[12];
    const float* Wk    = (const float*)d_in[13];
    const float* bk    = (const float*)d_in[14];
    const float* pbs   = (const float*)d_in[15];
    float* out = (float*)d_out;

    float* ws    = (float*)d_ws;
    float* gi    = ws + OFF_GI;
    float* gibar = ws + OFF_GIBAR;
    float* hend  = ws + OFF_HEND;
    float* gall  = ws + OFF_GALL;
    float* kmat  = ws + OFF_KMAT;
    uint4* wfn   = (uint4*)(ws + OFF_WFN);
    uint4* wfb   = (uint4*)(ws + OFF_WFB);
    uint4* wfihn = (uint4*)(ws + OFF_WFIHN);
    uint4* wfihb = (uint4*)(ws + OFF_WFIHB);
    int* ipos    = (int*)((char*)d_ws + OFF_INT_BYTES);
    int* ilastk  = ipos + NB * SEQ;
    int* inmask  = ilastk + NB * SEQ;
    int* isS     = inmask + NB;
    int* isLen   = isS + NB * SEQ;
    int* isC     = isLen + NB * SEQ;
    int* inseg   = isC + NB * SEQ;

    k_scan<<<1, 256, 0, stream>>>(mask, ipos, ilastk, inmask, isS, isLen, isC, inseg);
    k_wfrag<<<96, 256, 0, stream>>>(Whh_n, wfn, DB, 8);
    k_wfrag<<<96, 256, 0, stream>>>(Whh_b, wfb, DB, 8);
    k_wfrag<<<192, 256, 0, stream>>>(Wih_n, wfihn, DM, 16);
    k_wfrag<<<96, 256, 0, stream>>>(Wih_b, wfihb, DB, 8);
    k_keys<<<NB * TOCT, 64, 0, stream>>>(onset, Wk, bk, kmat);
    k_gemm_mfma<false><<<dim3(64, 12), 256, 0, stream>>>(DM, 16, te, wfihn, bih_n, gi, inmask);
    k_gru<0><<<256, 512, 0, stream>>>(wfn, bhh_n, gi, isS, isLen, isC, inseg, inmask, hend);
    k_gemm_mfma<true><<<dim3(64, 12), 256, 0, stream>>>(DB, 8, hend, wfihb, bih_b, gibar, inmask);
    k_gru<1><<<1, 512, 0, stream>>>(wfb, bhh_b, gibar, isS, isLen, isC, inseg, inmask, gall);
    k_fill<<<NB * SEQ, 256, 0, stream>>>(gall, ilastk, inmask, out);
    k_attn<<<NB * SEQ, 256, 0, stream>>>(gall, Wq, bq, kmat, ipos, inmask, pbs, out);
}